// Round 8
// baseline (7726.904 us; speedup 1.0000x reference)
//
#include <hip/hip_runtime.h>

#define HDIM  1024
#define FOURH 4096
#define TSEQ  2048
#define NCLS  512

// ---- fused pipeline config: grid = 3*64 + 2*32 = 256 blocks x 512 thr ----
#define SCANB  64       // scan blocks per layer
#define GEMMB  32       // gemm blocks per group
#define U16    16       // hidden units per scan block
#define DRING  128      // h-ring depth (steps)
#define GXRING 128      // gx-ring depth (steps)
#define CHUNK  64       // gx chunk (steps)
#define NCHUNK 32       // 2048/64

// sync offsets (u32 units)
#define CNT0 0          // [32] chunk-arrive, gemm group 0
#define CNT1 64         // [32] chunk-arrive, gemm group 1
#define CD0  128        // chunks_done, group 0
#define CD1  192        // chunks_done, group 1
#define SP1  256        // scan progress, layer 1
#define SP2  320        // scan progress, layer 2
#define SYNC_BYTES 2048
#define HDR_BYTES 32768

typedef float v2f __attribute__((ext_vector_type(2)));

// ---------------------------------------------------------------------------
union SharedU {
    struct { float h[HDIM]; float gate[4][U16]; } scan;      // ~4.4 KB
    struct { float As[16][72]; float Bs[16][132]; } gemm;    // ~12.8 KB
};

__device__ __forceinline__ unsigned long long ald(const unsigned long long* p) {
    return __hip_atomic_load(p, __ATOMIC_RELAXED, __HIP_MEMORY_SCOPE_AGENT);
}
__device__ __forceinline__ void ast(unsigned long long* p, unsigned long long v) {
    __hip_atomic_store(p, v, __ATOMIC_RELAXED, __HIP_MEMORY_SCOPE_AGENT);
}
__device__ __forceinline__ unsigned ald32(const unsigned* p) {
    return __hip_atomic_load(p, __ATOMIC_RELAXED, __HIP_MEMORY_SCOPE_AGENT);
}
__device__ __forceinline__ void ast32(unsigned* p, unsigned v) {
    __hip_atomic_store(p, v, __ATOMIC_RELAXED, __HIP_MEMORY_SCOPE_AGENT);
}

__device__ __forceinline__ float fsig(float x)  { return 1.f / (1.f + __expf(-x)); }
// fast tanh: saturates to +/-1 at exp saturation, err ~1e-6 (proven r1/r2)
__device__ __forceinline__ float ftanh(float x) { return 1.f - 2.f / (1.f + __expf(2.f * x)); }

// ---------------------------------------------------------------------------
// GEMM: C[M,N] = A[M,K] * B[N,K]^T + bias1[N] (+ bias2[N] if non-null)
// (gx0 pre-pass and final FC) — unchanged, proven.
// ---------------------------------------------------------------------------
__global__ __launch_bounds__(256) void gemm_bias_kernel(
    const float* __restrict__ A, const float* __restrict__ B,
    const float* __restrict__ bias1, const float* __restrict__ bias2,
    float* __restrict__ C, int M, int N, int K)
{
    __shared__ float As[16][68];
    __shared__ float Bs[16][68];

    const int tid = threadIdx.x;
    const int tx = tid & 15;
    const int ty = tid >> 4;
    const int n0 = blockIdx.x * 64;
    const int m0 = blockIdx.y * 64;
    const int r  = tid >> 2;
    const int kq = tid & 3;

    float acc[4][4];
#pragma unroll
    for (int i = 0; i < 4; ++i)
#pragma unroll
        for (int j = 0; j < 4; ++j) acc[i][j] = 0.f;

    for (int k0 = 0; k0 < K; k0 += 16) {
        float4 va = *(const float4*)&A[(size_t)(m0 + r) * K + k0 + 4 * kq];
        float4 vb = *(const float4*)&B[(size_t)(n0 + r) * K + k0 + 4 * kq];
        As[4 * kq + 0][r] = va.x; As[4 * kq + 1][r] = va.y;
        As[4 * kq + 2][r] = va.z; As[4 * kq + 3][r] = va.w;
        Bs[4 * kq + 0][r] = vb.x; Bs[4 * kq + 1][r] = vb.y;
        Bs[4 * kq + 2][r] = vb.z; Bs[4 * kq + 3][r] = vb.w;
        __syncthreads();
#pragma unroll
        for (int kk = 0; kk < 16; ++kk) {
            float4 a = *(const float4*)&As[kk][4 * ty];
            float4 b = *(const float4*)&Bs[kk][4 * tx];
            acc[0][0] = fmaf(a.x, b.x, acc[0][0]);
            acc[0][1] = fmaf(a.x, b.y, acc[0][1]);
            acc[0][2] = fmaf(a.x, b.z, acc[0][2]);
            acc[0][3] = fmaf(a.x, b.w, acc[0][3]);
            acc[1][0] = fmaf(a.y, b.x, acc[1][0]);
            acc[1][1] = fmaf(a.y, b.y, acc[1][1]);
            acc[1][2] = fmaf(a.y, b.z, acc[1][2]);
            acc[1][3] = fmaf(a.y, b.w, acc[1][3]);
            acc[2][0] = fmaf(a.z, b.x, acc[2][0]);
            acc[2][1] = fmaf(a.z, b.y, acc[2][1]);
            acc[2][2] = fmaf(a.z, b.z, acc[2][2]);
            acc[2][3] = fmaf(a.z, b.w, acc[2][3]);
            acc[3][0] = fmaf(a.w, b.x, acc[3][0]);
            acc[3][1] = fmaf(a.w, b.y, acc[3][1]);
            acc[3][2] = fmaf(a.w, b.z, acc[3][2]);
            acc[3][3] = fmaf(a.w, b.w, acc[3][3]);
        }
        __syncthreads();
    }

    float4 bv = *(const float4*)&bias1[n0 + 4 * tx];
    if (bias2) {
        float4 b2 = *(const float4*)&bias2[n0 + 4 * tx];
        bv.x += b2.x; bv.y += b2.y; bv.z += b2.z; bv.w += b2.w;
    }
#pragma unroll
    for (int i = 0; i < 4; ++i) {
        const int row = m0 + 4 * ty + i;
        float4 o;
        o.x = acc[i][0] + bv.x;
        o.y = acc[i][1] + bv.y;
        o.z = acc[i][2] + bv.z;
        o.w = acc[i][3] + bv.w;
        *(float4*)&C[(size_t)row * N + n0 + 4 * tx] = o;
    }
}

// ---------------------------------------------------------------------------
// PIPELINE scan role — r6 winner + SAFE critical-path trims (r7 retry):
// - gx row-value pre-gathered at prefetch time (1 shfl, off critical path);
//   row rg's gx lives in lane rg, so gxrow = shfl(gxs, lane&7). Folded after
//   the full cross-group reduce -> gate math bit-identical to r6.
// - barrier #1 replaced by LDS counter hcnt: waves write hstage, inc, then
//   go STRAIGHT to polling. wave7 spins hcnt, publishes the block's ONE
//   tagged 128B line. barrier A (after poll) guards the LDS h overwrite
//   (all waves past poll => all dots done); barrier B stages h(t).
// - poll: EVERY retry carries s_sleep(1) (r0-proven politeness; the r7
//   hot-spin variant is implicated in the container failures — never again).
// ---------------------------------------------------------------------------
#define LOAD_GXS(T) do { if (lane < 8) {                                      \
    gxs = __uint_as_float(ald32((const unsigned*)gxb +                        \
        (size_t)((T) & gxmask) * FOURH + (size_t)(lane >> 1) * HDIM           \
        + u0 + 2 * w + (lane & 1))); }                                        \
    gxrow = __shfl(gxs, lane & 7, 64); } while (0)

__device__ void scan_role(int bi,
    const float* __restrict__ Whh,
    const unsigned long long* __restrict__ gxb, unsigned gxmask,
    unsigned long long* __restrict__ ring,
    const unsigned* cdSrc,    // gx availability (null for layer 0)
    const unsigned* cdBp,     // h-ring backpressure (null for layer 2)
    unsigned* sp,             // scan progress out (null for layer 0)
    float* __restrict__ h2,   // layer-2 history out (else null)
    SharedU* sm, unsigned* hcnt)
{
    const int tid  = threadIdx.x;
    const int w    = tid >> 6;         // 0..7
    const int lane = tid & 63;
    const int uu   = lane & 1;
    const int u0   = bi * U16;

    // weights: 8 rows per wave = gates{0..3} x units{u0+2w, u0+2w+1}
    // row rg: gate = rg>>1, unit-parity = rg&1 (r4/r6-verified layout)
    v2f wv[8][8];
#pragma unroll
    for (int rg = 0; rg < 8; ++rg) {
        const float* Wr = Whh +
            (size_t)((rg >> 1) * HDIM + u0 + 2 * w + (rg & 1)) * HDIM;
#pragma unroll
        for (int j = 0; j < 4; ++j) {
            const float4 q = *(const float4*)(Wr + 256 * j + 4 * lane);
            v2f qa = {q.x, q.y}, qb = {q.z, q.w};
            wv[rg][2 * j]     = qa;
            wv[rg][2 * j + 1] = qb;
        }
    }
    { float2 z = {0.f, 0.f}; *(float2*)(sm->scan.h + 2 * tid) = z; }
    if (tid == 0) *hcnt = 0u;
    float cst = 0.f;                   // cell state (valid on lanes 0,1)
    float gxs = 0.f;                   // gx value (valid on lanes 0..7)
    float gxrow = 0.f;                 // gx of row (lane&7), pre-gathered
    unsigned cdc = 0u, bpc = 0u;       // cached progress counters
    __syncthreads();

    for (int t = 0; t < TSEQ; ++t) {
        // ring overwrite backpressure: wave7 lane0 only (publish gate)
        if (cdBp && t >= DRING && w == 7 && lane == 0) {
            const unsigned need = (unsigned)((t - DRING) >> 6) + 1u;
            while (bpc < need) {
                bpc = ald32(cdBp);
                if (bpc < need) __builtin_amdgcn_s_sleep(4);
            }
        }
        if ((t & (CHUNK - 1)) == 0) {
            if (cdSrc && lane == 0) {           // each wave's lane0, cached
                const unsigned need = (unsigned)(t >> 6) + 1u;
                while (cdc < need) {
                    cdc = ald32(cdSrc);
                    if (cdc < need) __builtin_amdgcn_s_sleep(4);
                }
            }
            LOAD_GXS(t);
        }

        // dots: 8 rows/wave, packed f32 pairs (h staged at barrier B of t-1)
        v2f acc2[8];
#pragma unroll
        for (int rg = 0; rg < 8; ++rg) { v2f z = {0.f, 0.f}; acc2[rg] = z; }
#pragma unroll
        for (int j = 0; j < 4; ++j) {
            const float4 hq = *(const float4*)(sm->scan.h + 256 * j + 4 * lane);
            const v2f hA = {hq.x, hq.y};
            const v2f hB = {hq.z, hq.w};
#pragma unroll
            for (int rg = 0; rg < 8; ++rg) {
                acc2[rg] = __builtin_elementwise_fma(wv[rg][2 * j],     hA, acc2[rg]);
                acc2[rg] = __builtin_elementwise_fma(wv[rg][2 * j + 1], hB, acc2[rg]);
            }
        }
        float a[8];
#pragma unroll
        for (int rg = 0; rg < 8; ++rg) a[rg] = acc2[rg].x + acc2[rg].y;

        // reduce (r4/r6-verified): 3-stage intra-8, select, 3-stage cross
#pragma unroll
        for (int off = 1; off <= 4; off <<= 1)
#pragma unroll
            for (int rg = 0; rg < 8; ++rg)
                a[rg] += __shfl_xor(a[rg], off, 64);
        const int l7 = lane & 7;
        const float s0 = (l7 & 1) ? a[1] : a[0];
        const float s1 = (l7 & 1) ? a[3] : a[2];
        const float s2 = (l7 & 1) ? a[5] : a[4];
        const float s3 = (l7 & 1) ? a[7] : a[6];
        const float t0 = (l7 & 2) ? s1 : s0;
        const float t1 = (l7 & 2) ? s3 : s2;
        float x = (l7 & 4) ? t1 : t0;       // lane L: partial of row (L&7)
        x += __shfl_xor(x, 8, 64);
        x += __shfl_xor(x, 16, 64);
        x += __shfl_xor(x, 32, 64);         // lane L: total of row (L&7)
        x += gxrow;                          // + gx (same assoc as r6)

        // gather 4 gates for this lane's unit; pointwise on lanes 0,1
        float gsum[4];
#pragma unroll
        for (int g = 0; g < 4; ++g)
            gsum[g] = __shfl(x, 2 * g + uu, 64);
        {
            const float si = fsig(gsum[0]), sf = fsig(gsum[1]);
            const float tg = ftanh(gsum[2]), so = fsig(gsum[3]);
            cst = sf * cst + si * tg;
            const float hval = so * ftanh(cst);
            if (lane < 2) {
                sm->scan.gate[0][2 * w + lane] = hval;   // hstage
                if (h2) h2[(size_t)t * HDIM + u0 + 2 * w + lane] = hval;
            }
        }
        asm volatile("s_waitcnt lgkmcnt(0)" ::: "memory");  // hstage visible
        if (lane == 0)
            __hip_atomic_fetch_add(hcnt, 1u, __ATOMIC_RELAXED,
                                   __HIP_MEMORY_SCOPE_WORKGROUP);

        const unsigned tag = (unsigned)(t + 1);
        if (w == 7) {
            // wait for all 8 waves' hstage, then publish ONE 128B line
            const unsigned needC = 8u * (unsigned)(t + 1);
            while (__hip_atomic_load(hcnt, __ATOMIC_RELAXED,
                                     __HIP_MEMORY_SCOPE_WORKGROUP) < needC) {}
            asm volatile("s_waitcnt lgkmcnt(0)" ::: "memory");
            __builtin_amdgcn_sched_barrier(0);
            if (lane < U16) {
                const float h = sm->scan.gate[0][lane];
                ast(ring + (size_t)(t & (DRING - 1)) * HDIM + u0 + lane,
                    ((unsigned long long)tag << 32) |
                    (unsigned long long)__float_as_uint(h));
            }
            if (sp && bi == 0 && lane == 0) ast32(sp, (unsigned)t);
        }
        if (((t + 1) & (CHUNK - 1)) != 0 && t + 1 < TSEQ) LOAD_GXS(t + 1);

        // restage h(t): direct tagged 2-entry poll into registers (polite
        // backoff EVERY retry), then barrier A, LDS write, barrier B.
        if (t + 1 < TSEQ) {
            const unsigned long long* hb = ring + (size_t)(t & (DRING - 1)) * HDIM;
            unsigned long long v0 = 0, v1 = 0;
            bool got0 = false, got1 = false;
            while (!(got0 && got1)) {
                if (!got0) {
                    const unsigned long long y = ald(hb + 2 * tid);
                    if ((unsigned)(y >> 32) == tag) { v0 = y; got0 = true; }
                }
                if (!got1) {
                    const unsigned long long y = ald(hb + 2 * tid + 1);
                    if ((unsigned)(y >> 32) == tag) { v1 = y; got1 = true; }
                }
                if (!(got0 && got1)) __builtin_amdgcn_s_sleep(1);
            }
            __syncthreads();   // barrier A: all waves past poll => dots done
            sm->scan.h[2 * tid]     = __uint_as_float((unsigned)v0);
            sm->scan.h[2 * tid + 1] = __uint_as_float((unsigned)v1);
            __syncthreads();   // barrier B: h(t) staged for all waves
        }
    }
}

// ---------------------------------------------------------------------------
// PIPELINE gemm role: 32 blocks x 512 thr per group; 128-col x 64-row chunks.
// (r0-proven version: per-entry tag-poll A staging)
// ---------------------------------------------------------------------------
__device__ void gemm_role(int tix,
    const unsigned long long* __restrict__ ringS,
    const float* __restrict__ Wih,
    const float* __restrict__ bih, const float* __restrict__ bhh,
    float* __restrict__ gxr,
    unsigned* cnt, unsigned* cd, const unsigned* spC,
    SharedU* sm)
{
    const int tid = threadIdx.x;
    const int tx = tid & 31, ty = tid >> 5;   // compute map: 128 cols, 64 rows
    const int n0 = tix * 128;
    const int tt = tid >> 3, ke = tid & 7;    // A staging: row tt, k-pair 2*ke
    const int cB = tid >> 2, kq = tid & 3;    // B staging: col cB, k-quad 4*kq

    float4 bv;
    {
        const float4 b1 = *(const float4*)(bih + n0 + 4 * tx);
        const float4 b2 = *(const float4*)(bhh + n0 + 4 * tx);
        bv.x = b1.x + b2.x; bv.y = b1.y + b2.y;
        bv.z = b1.z + b2.z; bv.w = b1.w + b2.w;
    }
    unsigned long long* gxr64 = (unsigned long long*)gxr;

    for (int q = 0; q < NCHUNK; ++q) {
        // gx-ring overwrite backpressure (victims = chunk q-2)
        if (q >= GXRING / CHUNK && tid == 0) {
            const unsigned need = (unsigned)((q - GXRING / CHUNK + 1) * CHUNK + 2);
            while (ald32(spC) < need) __builtin_amdgcn_s_sleep(8);
        }
        __syncthreads();

        float acc[4][4];
#pragma unroll
        for (int i = 0; i < 4; ++i)
#pragma unroll
            for (int j = 0; j < 4; ++j) acc[i][j] = 0.f;

        for (int k0 = 0; k0 < HDIM; k0 += 16) {
            {   // stage A (h chunk) with tag-poll: As[k][t]
                const int trow = q * CHUNK + tt;
                const unsigned expt = (unsigned)(trow + 1);
                const unsigned long long* srcp =
                    ringS + (size_t)(trow & (DRING - 1)) * HDIM + k0 + 2 * ke;
#pragma unroll
                for (int e = 0; e < 2; ++e) {
                    unsigned long long x;
                    while ((unsigned)((x = ald(srcp + e)) >> 32) != expt)
                        __builtin_amdgcn_s_sleep(1);
                    sm->gemm.As[2 * ke + e][tt] = __uint_as_float((unsigned)x);
                }
            }
            {   // stage B (W_ih tile)
                const float4 vb = *(const float4*)(Wih + (size_t)(n0 + cB) * HDIM + k0 + 4 * kq);
                sm->gemm.Bs[4 * kq + 0][cB] = vb.x;
                sm->gemm.Bs[4 * kq + 1][cB] = vb.y;
                sm->gemm.Bs[4 * kq + 2][cB] = vb.z;
                sm->gemm.Bs[4 * kq + 3][cB] = vb.w;
            }
            __syncthreads();
#pragma unroll
            for (int kk = 0; kk < 16; ++kk) {
                const float4 a = *(const float4*)&sm->gemm.As[kk][4 * ty];
                const float4 b = *(const float4*)&sm->gemm.Bs[kk][4 * tx];
                acc[0][0] = fmaf(a.x, b.x, acc[0][0]);
                acc[0][1] = fmaf(a.x, b.y, acc[0][1]);
                acc[0][2] = fmaf(a.x, b.z, acc[0][2]);
                acc[0][3] = fmaf(a.x, b.w, acc[0][3]);
                acc[1][0] = fmaf(a.y, b.x, acc[1][0]);
                acc[1][1] = fmaf(a.y, b.y, acc[1][1]);
                acc[1][2] = fmaf(a.y, b.z, acc[1][2]);
                acc[1][3] = fmaf(a.y, b.w, acc[1][3]);
                acc[2][0] = fmaf(a.z, b.x, acc[2][0]);
                acc[2][1] = fmaf(a.z, b.y, acc[2][1]);
                acc[2][2] = fmaf(a.z, b.z, acc[2][2]);
                acc[2][3] = fmaf(a.z, b.w, acc[2][3]);
                acc[3][0] = fmaf(a.w, b.x, acc[3][0]);
                acc[3][1] = fmaf(a.w, b.y, acc[3][1]);
                acc[3][2] = fmaf(a.w, b.z, acc[3][2]);
                acc[3][3] = fmaf(a.w, b.w, acc[3][3]);
            }
            __syncthreads();
        }

#pragma unroll
        for (int i = 0; i < 4; ++i) {
            const int trow = q * CHUNK + 4 * ty + i;
            const float o0 = acc[i][0] + bv.x;
            const float o1 = acc[i][1] + bv.y;
            const float o2 = acc[i][2] + bv.z;
            const float o3 = acc[i][3] + bv.w;
            const size_t base =
                ((size_t)(trow & (GXRING - 1)) * FOURH + n0 + 4 * tx) / 2;
            ast(gxr64 + base,
                ((unsigned long long)__float_as_uint(o1) << 32) | __float_as_uint(o0));
            ast(gxr64 + base + 1,
                ((unsigned long long)__float_as_uint(o3) << 32) | __float_as_uint(o2));
        }
        asm volatile("s_waitcnt vmcnt(0)" ::: "memory");
        __syncthreads();
        if (tid == 0) {
            const unsigned old = __hip_atomic_fetch_add(cnt + q, 1u,
                                     __ATOMIC_RELAXED, __HIP_MEMORY_SCOPE_AGENT);
            if (old + 1u == (unsigned)GEMMB) ast32(cd, (unsigned)(q + 1));
        }
    }
}

// ---------------------------------------------------------------------------
__global__ __launch_bounds__(512, 2) void fused_scan(
    const float* __restrict__ gx0,
    const float* __restrict__ Whh0, const float* __restrict__ Whh1,
    const float* __restrict__ Whh2,
    const float* __restrict__ Wih1, const float* __restrict__ Wih2,
    const float* __restrict__ bih1, const float* __restrict__ bhh1,
    const float* __restrict__ bih2, const float* __restrict__ bhh2,
    unsigned long long* ring0, unsigned long long* ring1, unsigned long long* ring2,
    float* gxr1, float* gxr2,
    float* h2out, unsigned* syncw)
{
    __shared__ SharedU sm;
    __shared__ unsigned hcnt;
    const int lb = blockIdx.x;
    if (lb < 3 * SCANB) {
        const int layer = lb >> 6;
        const int bi    = lb & 63;
        if (layer == 0)
            scan_role(bi, Whh0, (const unsigned long long*)gx0, 2047u, ring0,
                      nullptr, syncw + CD0, nullptr, nullptr, &sm, &hcnt);
        else if (layer == 1)
            scan_role(bi, Whh1, (const unsigned long long*)gxr1, GXRING - 1u, ring1,
                      syncw + CD0, syncw + CD1, syncw + SP1, nullptr, &sm, &hcnt);
        else
            scan_role(bi, Whh2, (const unsigned long long*)gxr2, GXRING - 1u, ring2,
                      syncw + CD1, nullptr, syncw + SP2, h2out, &sm, &hcnt);
    } else {
        const int gb  = lb - 3 * SCANB;
        const int gl  = gb >> 5;
        const int tix = gb & 31;
        if (gl == 0)
            gemm_role(tix, ring0, Wih1, bih1, bhh1, gxr1,
                      syncw + CNT0, syncw + CD0, syncw + SP1, &sm);
        else
            gemm_role(tix, ring1, Wih2, bih2, bhh2, gxr2,
                      syncw + CNT1, syncw + CD1, syncw + SP2, &sm);
    }
}

// ---------------------------------------------------------------------------
extern "C" void kernel_launch(void* const* d_in, const int* in_sizes, int n_in,
                              void* d_out, int out_size, void* d_ws, size_t ws_size,
                              hipStream_t stream)
{
    (void)in_sizes; (void)n_in; (void)out_size; (void)ws_size;

    const float* x = (const float*)d_in[0];
    const float* W_ih[3] = {(const float*)d_in[1], (const float*)d_in[5], (const float*)d_in[9]};
    const float* W_hh[3] = {(const float*)d_in[2], (const float*)d_in[6], (const float*)d_in[10]};
    const float* b_ih[3] = {(const float*)d_in[3], (const float*)d_in[7], (const float*)d_in[11]};
    const float* b_hh[3] = {(const float*)d_in[4], (const float*)d_in[8], (const float*)d_in[12]};
    const float* fc_w = (const float*)d_in[13];
    const float* fc_b = (const float*)d_in[14];
    float* out = (float*)d_out;

    // ws: header 32KB | gx0 32MB | A 8MB (h2) | rings 3MB | gxr 4MB  (49.3MB)
    unsigned* syncw = (unsigned*)d_ws;
    float* gx = (float*)((char*)d_ws + HDR_BYTES);
    float* A  = gx + (size_t)TSEQ * FOURH;
    unsigned long long* ring0 = (unsigned long long*)(A + (size_t)TSEQ * HDIM);
    unsigned long long* ring1 = ring0 + (size_t)DRING * HDIM;
    unsigned long long* ring2 = ring1 + (size_t)DRING * HDIM;
    float* gxr1 = (float*)(ring2 + (size_t)DRING * HDIM);
    float* gxr2 = gxr1 + (size_t)GXRING * FOURH;

    hipMemsetAsync(syncw, 0, SYNC_BYTES, stream);

    // gx0 = x @ W_ih0^T + b_ih0 + b_hh0
    {
        dim3 g(FOURH / 64, TSEQ / 64);
        gemm_bias_kernel<<<g, 256, 0, stream>>>(x, W_ih[0], b_ih[0], b_hh[0],
                                                gx, TSEQ, FOURH, HDIM);
    }

    // fused 3-layer pipelined scan + on-the-fly gx GEMMs: 256 blocks x 512 thr
    {
        const float* gx0_c = gx;
        float* h2 = A;
        void* args[] = {
            (void*)&gx0_c,
            (void*)&W_hh[0], (void*)&W_hh[1], (void*)&W_hh[2],
            (void*)&W_ih[1], (void*)&W_ih[2],
            (void*)&b_ih[1], (void*)&b_hh[1],
            (void*)&b_ih[2], (void*)&b_hh[2],
            (void*)&ring0, (void*)&ring1, (void*)&ring2,
            (void*)&gxr1, (void*)&gxr2,
            (void*)&h2, (void*)&syncw
        };
        hipLaunchCooperativeKernel((void*)fused_scan,
                                   dim3(3 * SCANB + 2 * GEMMB), dim3(512),
                                   args, 0, stream);
    }

    // out = h2 @ fc_w^T + fc_b
    {
        dim3 g(NCLS / 64, TSEQ / 64);
        gemm_bias_kernel<<<g, 256, 0, stream>>>(A, fc_w, fc_b, nullptr,
                                                out, TSEQ, NCLS, HDIM);
    }
}

// Round 9
// 7662.830 us; speedup vs baseline: 1.0084x; 1.0084x over previous
//
#include <hip/hip_runtime.h>

#define HDIM  1024
#define FOURH 4096
#define TSEQ  2048
#define NCLS  512

// ---- fused pipeline config: grid = 3*64 + 2*32 = 256 blocks x 512 thr ----
#define SCANB  64       // scan blocks per layer
#define GEMMB  32       // gemm blocks per group
#define U16    16       // hidden units per scan block
#define DRING  128      // h-ring depth (steps)
#define GXRING 128      // gx-ring depth (steps)
#define CHUNK  64       // gx chunk (steps)
#define NCHUNK 32       // 2048/64

// sync offsets (u32 units)
#define CNT0 0          // [32] chunk-arrive, gemm group 0
#define CNT1 64         // [32] chunk-arrive, gemm group 1
#define CD0  128        // chunks_done, group 0
#define CD1  192        // chunks_done, group 1
#define SP1  256        // scan progress, layer 1
#define SP2  320        // scan progress, layer 2
#define SP0  384        // scan progress, layer 0 (new: gemm A-gate)
#define SYNC_BYTES 2048
#define HDR_BYTES 32768

typedef float v2f __attribute__((ext_vector_type(2)));
typedef unsigned int u32x4 __attribute__((ext_vector_type(4)));

// ---------------------------------------------------------------------------
union SharedU {
    struct { float h[HDIM]; float gate[4][U16]; } scan;      // ~4.4 KB
    struct { float As[16][72]; float Bs[16][132]; } gemm;    // ~12.8 KB
};

__device__ __forceinline__ unsigned long long ald(const unsigned long long* p) {
    return __hip_atomic_load(p, __ATOMIC_RELAXED, __HIP_MEMORY_SCOPE_AGENT);
}
__device__ __forceinline__ void ast(unsigned long long* p, unsigned long long v) {
    __hip_atomic_store(p, v, __ATOMIC_RELAXED, __HIP_MEMORY_SCOPE_AGENT);
}
__device__ __forceinline__ unsigned ald32(const unsigned* p) {
    return __hip_atomic_load(p, __ATOMIC_RELAXED, __HIP_MEMORY_SCOPE_AGENT);
}
__device__ __forceinline__ void ast32(unsigned* p, unsigned v) {
    __hip_atomic_store(p, v, __ATOMIC_RELAXED, __HIP_MEMORY_SCOPE_AGENT);
}
// 16B poll load, L1/L2-bypass (same visibility semantics as ald, 2 entries)
__device__ __forceinline__ u32x4 ald16B(const unsigned long long* p) {
    u32x4 y;
    asm volatile("global_load_dwordx4 %0, %1, off sc0 sc1\n\t"
                 "s_waitcnt vmcnt(0)"
                 : "=v"(y) : "v"(p) : "memory");
    return y;
}

__device__ __forceinline__ float fsig(float x)  { return 1.f / (1.f + __expf(-x)); }
// fast tanh: saturates to +/-1 at exp saturation, err ~1e-6 (proven r1/r2)
__device__ __forceinline__ float ftanh(float x) { return 1.f - 2.f / (1.f + __expf(2.f * x)); }

// ---------------------------------------------------------------------------
// GEMM: C[M,N] = A[M,K] * B[N,K]^T + bias1[N] (+ bias2[N] if non-null)
// (gx0 pre-pass and final FC) — unchanged, proven.
// ---------------------------------------------------------------------------
__global__ __launch_bounds__(256) void gemm_bias_kernel(
    const float* __restrict__ A, const float* __restrict__ B,
    const float* __restrict__ bias1, const float* __restrict__ bias2,
    float* __restrict__ C, int M, int N, int K)
{
    __shared__ float As[16][68];
    __shared__ float Bs[16][68];

    const int tid = threadIdx.x;
    const int tx = tid & 15;
    const int ty = tid >> 4;
    const int n0 = blockIdx.x * 64;
    const int m0 = blockIdx.y * 64;
    const int r  = tid >> 2;
    const int kq = tid & 3;

    float acc[4][4];
#pragma unroll
    for (int i = 0; i < 4; ++i)
#pragma unroll
        for (int j = 0; j < 4; ++j) acc[i][j] = 0.f;

    for (int k0 = 0; k0 < K; k0 += 16) {
        float4 va = *(const float4*)&A[(size_t)(m0 + r) * K + k0 + 4 * kq];
        float4 vb = *(const float4*)&B[(size_t)(n0 + r) * K + k0 + 4 * kq];
        As[4 * kq + 0][r] = va.x; As[4 * kq + 1][r] = va.y;
        As[4 * kq + 2][r] = va.z; As[4 * kq + 3][r] = va.w;
        Bs[4 * kq + 0][r] = vb.x; Bs[4 * kq + 1][r] = vb.y;
        Bs[4 * kq + 2][r] = vb.z; Bs[4 * kq + 3][r] = vb.w;
        __syncthreads();
#pragma unroll
        for (int kk = 0; kk < 16; ++kk) {
            float4 a = *(const float4*)&As[kk][4 * ty];
            float4 b = *(const float4*)&Bs[kk][4 * tx];
            acc[0][0] = fmaf(a.x, b.x, acc[0][0]);
            acc[0][1] = fmaf(a.x, b.y, acc[0][1]);
            acc[0][2] = fmaf(a.x, b.z, acc[0][2]);
            acc[0][3] = fmaf(a.x, b.w, acc[0][3]);
            acc[1][0] = fmaf(a.y, b.x, acc[1][0]);
            acc[1][1] = fmaf(a.y, b.y, acc[1][1]);
            acc[1][2] = fmaf(a.y, b.z, acc[1][2]);
            acc[1][3] = fmaf(a.y, b.w, acc[1][3]);
            acc[2][0] = fmaf(a.z, b.x, acc[2][0]);
            acc[2][1] = fmaf(a.z, b.y, acc[2][1]);
            acc[2][2] = fmaf(a.z, b.z, acc[2][2]);
            acc[2][3] = fmaf(a.z, b.w, acc[2][3]);
            acc[3][0] = fmaf(a.w, b.x, acc[3][0]);
            acc[3][1] = fmaf(a.w, b.y, acc[3][1]);
            acc[3][2] = fmaf(a.w, b.z, acc[3][2]);
            acc[3][3] = fmaf(a.w, b.w, acc[3][3]);
        }
        __syncthreads();
    }

    float4 bv = *(const float4*)&bias1[n0 + 4 * tx];
    if (bias2) {
        float4 b2 = *(const float4*)&bias2[n0 + 4 * tx];
        bv.x += b2.x; bv.y += b2.y; bv.z += b2.z; bv.w += b2.w;
    }
#pragma unroll
    for (int i = 0; i < 4; ++i) {
        const int row = m0 + 4 * ty + i;
        float4 o;
        o.x = acc[i][0] + bv.x;
        o.y = acc[i][1] + bv.y;
        o.z = acc[i][2] + bv.z;
        o.w = acc[i][3] + bv.w;
        *(float4*)&C[(size_t)row * N + n0 + 4 * tx] = o;
    }
}

// ---------------------------------------------------------------------------
// PIPELINE scan role — r8 structure (proven) + 16B poll loads:
// restage poll now issues ONE dwordx4 (both entries) per retry instead of
// two dwordx2 — halves scan-side MALL transactions; each 8B half is still
// tag-checked independently (producer writes each half atomically).
// ---------------------------------------------------------------------------
#define LOAD_GXS(T) do { if (lane < 8) {                                      \
    gxs = __uint_as_float(ald32((const unsigned*)gxb +                        \
        (size_t)((T) & gxmask) * FOURH + (size_t)(lane >> 1) * HDIM           \
        + u0 + 2 * w + (lane & 1))); }                                        \
    gxrow = __shfl(gxs, lane & 7, 64); } while (0)

__device__ void scan_role(int bi,
    const float* __restrict__ Whh,
    const unsigned long long* __restrict__ gxb, unsigned gxmask,
    unsigned long long* __restrict__ ring,
    const unsigned* cdSrc,    // gx availability (null for layer 0)
    const unsigned* cdBp,     // h-ring backpressure (null for layer 2)
    unsigned* sp,             // scan progress out (all layers now)
    float* __restrict__ h2,   // layer-2 history out (else null)
    SharedU* sm, unsigned* hcnt)
{
    const int tid  = threadIdx.x;
    const int w    = tid >> 6;         // 0..7
    const int lane = tid & 63;
    const int uu   = lane & 1;
    const int u0   = bi * U16;

    // weights: 8 rows per wave = gates{0..3} x units{u0+2w, u0+2w+1}
    // row rg: gate = rg>>1, unit-parity = rg&1 (r4/r6-verified layout)
    v2f wv[8][8];
#pragma unroll
    for (int rg = 0; rg < 8; ++rg) {
        const float* Wr = Whh +
            (size_t)((rg >> 1) * HDIM + u0 + 2 * w + (rg & 1)) * HDIM;
#pragma unroll
        for (int j = 0; j < 4; ++j) {
            const float4 q = *(const float4*)(Wr + 256 * j + 4 * lane);
            v2f qa = {q.x, q.y}, qb = {q.z, q.w};
            wv[rg][2 * j]     = qa;
            wv[rg][2 * j + 1] = qb;
        }
    }
    { float2 z = {0.f, 0.f}; *(float2*)(sm->scan.h + 2 * tid) = z; }
    if (tid == 0) *hcnt = 0u;
    float cst = 0.f;                   // cell state (valid on lanes 0,1)
    float gxs = 0.f;                   // gx value (valid on lanes 0..7)
    float gxrow = 0.f;                 // gx of row (lane&7), pre-gathered
    unsigned cdc = 0u, bpc = 0u;       // cached progress counters
    __syncthreads();

    for (int t = 0; t < TSEQ; ++t) {
        // ring overwrite backpressure: wave7 lane0 only (publish gate)
        if (cdBp && t >= DRING && w == 7 && lane == 0) {
            const unsigned need = (unsigned)((t - DRING) >> 6) + 1u;
            while (bpc < need) {
                bpc = ald32(cdBp);
                if (bpc < need) __builtin_amdgcn_s_sleep(4);
            }
        }
        if ((t & (CHUNK - 1)) == 0) {
            if (cdSrc && lane == 0) {           // each wave's lane0, cached
                const unsigned need = (unsigned)(t >> 6) + 1u;
                while (cdc < need) {
                    cdc = ald32(cdSrc);
                    if (cdc < need) __builtin_amdgcn_s_sleep(4);
                }
            }
            LOAD_GXS(t);
        }

        // dots: 8 rows/wave, packed f32 pairs (h staged at barrier B of t-1)
        v2f acc2[8];
#pragma unroll
        for (int rg = 0; rg < 8; ++rg) { v2f z = {0.f, 0.f}; acc2[rg] = z; }
#pragma unroll
        for (int j = 0; j < 4; ++j) {
            const float4 hq = *(const float4*)(sm->scan.h + 256 * j + 4 * lane);
            const v2f hA = {hq.x, hq.y};
            const v2f hB = {hq.z, hq.w};
#pragma unroll
            for (int rg = 0; rg < 8; ++rg) {
                acc2[rg] = __builtin_elementwise_fma(wv[rg][2 * j],     hA, acc2[rg]);
                acc2[rg] = __builtin_elementwise_fma(wv[rg][2 * j + 1], hB, acc2[rg]);
            }
        }
        float a[8];
#pragma unroll
        for (int rg = 0; rg < 8; ++rg) a[rg] = acc2[rg].x + acc2[rg].y;

        // reduce (r4/r6-verified): 3-stage intra-8, select, 3-stage cross
#pragma unroll
        for (int off = 1; off <= 4; off <<= 1)
#pragma unroll
            for (int rg = 0; rg < 8; ++rg)
                a[rg] += __shfl_xor(a[rg], off, 64);
        const int l7 = lane & 7;
        const float s0 = (l7 & 1) ? a[1] : a[0];
        const float s1 = (l7 & 1) ? a[3] : a[2];
        const float s2 = (l7 & 1) ? a[5] : a[4];
        const float s3 = (l7 & 1) ? a[7] : a[6];
        const float t0 = (l7 & 2) ? s1 : s0;
        const float t1 = (l7 & 2) ? s3 : s2;
        float x = (l7 & 4) ? t1 : t0;       // lane L: partial of row (L&7)
        x += __shfl_xor(x, 8, 64);
        x += __shfl_xor(x, 16, 64);
        x += __shfl_xor(x, 32, 64);         // lane L: total of row (L&7)
        x += gxrow;                          // + gx (same assoc as r6)

        // gather 4 gates for this lane's unit; pointwise on lanes 0,1
        float gsum[4];
#pragma unroll
        for (int g = 0; g < 4; ++g)
            gsum[g] = __shfl(x, 2 * g + uu, 64);
        {
            const float si = fsig(gsum[0]), sf = fsig(gsum[1]);
            const float tg = ftanh(gsum[2]), so = fsig(gsum[3]);
            cst = sf * cst + si * tg;
            const float hval = so * ftanh(cst);
            if (lane < 2) {
                sm->scan.gate[0][2 * w + lane] = hval;   // hstage
                if (h2) h2[(size_t)t * HDIM + u0 + 2 * w + lane] = hval;
            }
        }
        asm volatile("s_waitcnt lgkmcnt(0)" ::: "memory");  // hstage visible
        if (lane == 0)
            __hip_atomic_fetch_add(hcnt, 1u, __ATOMIC_RELAXED,
                                   __HIP_MEMORY_SCOPE_WORKGROUP);

        const unsigned tag = (unsigned)(t + 1);
        if (w == 7) {
            // wait for all 8 waves' hstage, then publish ONE 128B line
            const unsigned needC = 8u * (unsigned)(t + 1);
            while (__hip_atomic_load(hcnt, __ATOMIC_RELAXED,
                                     __HIP_MEMORY_SCOPE_WORKGROUP) < needC) {}
            asm volatile("s_waitcnt lgkmcnt(0)" ::: "memory");
            __builtin_amdgcn_sched_barrier(0);
            if (lane < U16) {
                const float h = sm->scan.gate[0][lane];
                ast(ring + (size_t)(t & (DRING - 1)) * HDIM + u0 + lane,
                    ((unsigned long long)tag << 32) |
                    (unsigned long long)__float_as_uint(h));
            }
            if (sp && bi == 0 && lane == 0) ast32(sp, (unsigned)t);
        }
        if (((t + 1) & (CHUNK - 1)) != 0 && t + 1 < TSEQ) LOAD_GXS(t + 1);

        // restage h(t): ONE 16B tagged poll per thread (polite backoff),
        // then barrier A (all dots done), LDS write, barrier B.
        if (t + 1 < TSEQ) {
            const unsigned long long* hb = ring + (size_t)(t & (DRING - 1)) * HDIM;
            const unsigned long long* addr = hb + 2 * tid;
            unsigned h0 = 0, h1 = 0;
            bool got0 = false, got1 = false;
            while (!(got0 && got1)) {
                const u32x4 y = ald16B(addr);
                if (!got0 && y.y == tag) { h0 = y.x; got0 = true; }
                if (!got1 && y.w == tag) { h1 = y.z; got1 = true; }
                if (!(got0 && got1)) __builtin_amdgcn_s_sleep(1);
            }
            __syncthreads();   // barrier A: all waves past poll => dots done
            sm->scan.h[2 * tid]     = __uint_as_float(h0);
            sm->scan.h[2 * tid + 1] = __uint_as_float(h1);
            __syncthreads();   // barrier B: h(t) staged for all waves
        }
    }
}

// ---------------------------------------------------------------------------
// PIPELINE gemm role: 32 blocks x 512 thr per group; 128-col x 64-row chunks.
// NEW: A-staging is gated on the SOURCE LAYER's progress counter — the k0
// loop starts only once the chunk's last row is published. k0=0 needed all
// 64 rows anyway, so the gate costs no latency; it deletes the poll storm
// (previously ~40 futile MALL loads/cycle hammering the fabric the scan
// broadcast depends on). Per-entry tag-poll retained for correctness.
// ---------------------------------------------------------------------------
__device__ void gemm_role(int tix,
    const unsigned long long* __restrict__ ringS,
    const unsigned* __restrict__ spA,    // source-layer progress (A-gate)
    const float* __restrict__ Wih,
    const float* __restrict__ bih, const float* __restrict__ bhh,
    float* __restrict__ gxr,
    unsigned* cnt, unsigned* cd, const unsigned* spC,
    SharedU* sm)
{
    const int tid = threadIdx.x;
    const int tx = tid & 31, ty = tid >> 5;   // compute map: 128 cols, 64 rows
    const int n0 = tix * 128;
    const int tt = tid >> 3, ke = tid & 7;    // A staging: row tt, k-pair 2*ke
    const int cB = tid >> 2, kq = tid & 3;    // B staging: col cB, k-quad 4*kq

    float4 bv;
    {
        const float4 b1 = *(const float4*)(bih + n0 + 4 * tx);
        const float4 b2 = *(const float4*)(bhh + n0 + 4 * tx);
        bv.x = b1.x + b2.x; bv.y = b1.y + b2.y;
        bv.z = b1.z + b2.z; bv.w = b1.w + b2.w;
    }
    unsigned long long* gxr64 = (unsigned long long*)gxr;

    for (int q = 0; q < NCHUNK; ++q) {
        // gx-ring overwrite backpressure (victims = chunk q-2)
        if (q >= GXRING / CHUNK && tid == 0) {
            const unsigned need = (unsigned)((q - GXRING / CHUNK + 1) * CHUNK + 2);
            while (ald32(spC) < need) __builtin_amdgcn_s_sleep(8);
        }
        // A-gate: wait until the source layer has published this chunk's
        // last row (sp stores the just-completed step t; need t >= q*64+63).
        if (tid == 0) {
            const unsigned needA = (unsigned)(q * CHUNK + CHUNK - 1);
            while (ald32(spA) < needA) __builtin_amdgcn_s_sleep(16);
        }
        __syncthreads();

        float acc[4][4];
#pragma unroll
        for (int i = 0; i < 4; ++i)
#pragma unroll
            for (int j = 0; j < 4; ++j) acc[i][j] = 0.f;

        for (int k0 = 0; k0 < HDIM; k0 += 16) {
            {   // stage A (h chunk) with tag-poll: As[k][t]
                const int trow = q * CHUNK + tt;
                const unsigned expt = (unsigned)(trow + 1);
                const unsigned long long* srcp =
                    ringS + (size_t)(trow & (DRING - 1)) * HDIM + k0 + 2 * ke;
#pragma unroll
                for (int e = 0; e < 2; ++e) {
                    unsigned long long x;
                    while ((unsigned)((x = ald(srcp + e)) >> 32) != expt)
                        __builtin_amdgcn_s_sleep(1);
                    sm->gemm.As[2 * ke + e][tt] = __uint_as_float((unsigned)x);
                }
            }
            {   // stage B (W_ih tile)
                const float4 vb = *(const float4*)(Wih + (size_t)(n0 + cB) * HDIM + k0 + 4 * kq);
                sm->gemm.Bs[4 * kq + 0][cB] = vb.x;
                sm->gemm.Bs[4 * kq + 1][cB] = vb.y;
                sm->gemm.Bs[4 * kq + 2][cB] = vb.z;
                sm->gemm.Bs[4 * kq + 3][cB] = vb.w;
            }
            __syncthreads();
#pragma unroll
            for (int kk = 0; kk < 16; ++kk) {
                const float4 a = *(const float4*)&sm->gemm.As[kk][4 * ty];
                const float4 b = *(const float4*)&sm->gemm.Bs[kk][4 * tx];
                acc[0][0] = fmaf(a.x, b.x, acc[0][0]);
                acc[0][1] = fmaf(a.x, b.y, acc[0][1]);
                acc[0][2] = fmaf(a.x, b.z, acc[0][2]);
                acc[0][3] = fmaf(a.x, b.w, acc[0][3]);
                acc[1][0] = fmaf(a.y, b.x, acc[1][0]);
                acc[1][1] = fmaf(a.y, b.y, acc[1][1]);
                acc[1][2] = fmaf(a.y, b.z, acc[1][2]);
                acc[1][3] = fmaf(a.y, b.w, acc[1][3]);
                acc[2][0] = fmaf(a.z, b.x, acc[2][0]);
                acc[2][1] = fmaf(a.z, b.y, acc[2][1]);
                acc[2][2] = fmaf(a.z, b.z, acc[2][2]);
                acc[2][3] = fmaf(a.z, b.w, acc[2][3]);
                acc[3][0] = fmaf(a.w, b.x, acc[3][0]);
                acc[3][1] = fmaf(a.w, b.y, acc[3][1]);
                acc[3][2] = fmaf(a.w, b.z, acc[3][2]);
                acc[3][3] = fmaf(a.w, b.w, acc[3][3]);
            }
            __syncthreads();
        }

#pragma unroll
        for (int i = 0; i < 4; ++i) {
            const int trow = q * CHUNK + 4 * ty + i;
            const float o0 = acc[i][0] + bv.x;
            const float o1 = acc[i][1] + bv.y;
            const float o2 = acc[i][2] + bv.z;
            const float o3 = acc[i][3] + bv.w;
            const size_t base =
                ((size_t)(trow & (GXRING - 1)) * FOURH + n0 + 4 * tx) / 2;
            ast(gxr64 + base,
                ((unsigned long long)__float_as_uint(o1) << 32) | __float_as_uint(o0));
            ast(gxr64 + base + 1,
                ((unsigned long long)__float_as_uint(o3) << 32) | __float_as_uint(o2));
        }
        asm volatile("s_waitcnt vmcnt(0)" ::: "memory");
        __syncthreads();
        if (tid == 0) {
            const unsigned old = __hip_atomic_fetch_add(cnt + q, 1u,
                                     __ATOMIC_RELAXED, __HIP_MEMORY_SCOPE_AGENT);
            if (old + 1u == (unsigned)GEMMB) ast32(cd, (unsigned)(q + 1));
        }
    }
}

// ---------------------------------------------------------------------------
__global__ __launch_bounds__(512, 2) void fused_scan(
    const float* __restrict__ gx0,
    const float* __restrict__ Whh0, const float* __restrict__ Whh1,
    const float* __restrict__ Whh2,
    const float* __restrict__ Wih1, const float* __restrict__ Wih2,
    const float* __restrict__ bih1, const float* __restrict__ bhh1,
    const float* __restrict__ bih2, const float* __restrict__ bhh2,
    unsigned long long* ring0, unsigned long long* ring1, unsigned long long* ring2,
    float* gxr1, float* gxr2,
    float* h2out, unsigned* syncw)
{
    __shared__ SharedU sm;
    __shared__ unsigned hcnt;
    const int lb = blockIdx.x;
    if (lb < 3 * SCANB) {
        const int layer = lb >> 6;
        const int bi    = lb & 63;
        if (layer == 0)
            scan_role(bi, Whh0, (const unsigned long long*)gx0, 2047u, ring0,
                      nullptr, syncw + CD0, syncw + SP0, nullptr, &sm, &hcnt);
        else if (layer == 1)
            scan_role(bi, Whh1, (const unsigned long long*)gxr1, GXRING - 1u, ring1,
                      syncw + CD0, syncw + CD1, syncw + SP1, nullptr, &sm, &hcnt);
        else
            scan_role(bi, Whh2, (const unsigned long long*)gxr2, GXRING - 1u, ring2,
                      syncw + CD1, nullptr, syncw + SP2, h2out, &sm, &hcnt);
    } else {
        const int gb  = lb - 3 * SCANB;
        const int gl  = gb >> 5;
        const int tix = gb & 31;
        if (gl == 0)
            gemm_role(tix, ring0, syncw + SP0, Wih1, bih1, bhh1, gxr1,
                      syncw + CNT0, syncw + CD0, syncw + SP1, &sm);
        else
            gemm_role(tix, ring1, syncw + SP1, Wih2, bih2, bhh2, gxr2,
                      syncw + CNT1, syncw + CD1, syncw + SP2, &sm);
    }
}

// ---------------------------------------------------------------------------
extern "C" void kernel_launch(void* const* d_in, const int* in_sizes, int n_in,
                              void* d_out, int out_size, void* d_ws, size_t ws_size,
                              hipStream_t stream)
{
    (void)in_sizes; (void)n_in; (void)out_size; (void)ws_size;

    const float* x = (const float*)d_in[0];
    const float* W_ih[3] = {(const float*)d_in[1], (const float*)d_in[5], (const float*)d_in[9]};
    const float* W_hh[3] = {(const float*)d_in[2], (const float*)d_in[6], (const float*)d_in[10]};
    const float* b_ih[3] = {(const float*)d_in[3], (const float*)d_in[7], (const float*)d_in[11]};
    const float* b_hh[3] = {(const float*)d_in[4], (const float*)d_in[8], (const float*)d_in[12]};
    const float* fc_w = (const float*)d_in[13];
    const float* fc_b = (const float*)d_in[14];
    float* out = (float*)d_out;

    // ws: header 32KB | gx0 32MB | A 8MB (h2) | rings 3MB | gxr 4MB  (49.3MB)
    unsigned* syncw = (unsigned*)d_ws;
    float* gx = (float*)((char*)d_ws + HDR_BYTES);
    float* A  = gx + (size_t)TSEQ * FOURH;
    unsigned long long* ring0 = (unsigned long long*)(A + (size_t)TSEQ * HDIM);
    unsigned long long* ring1 = ring0 + (size_t)DRING * HDIM;
    unsigned long long* ring2 = ring1 + (size_t)DRING * HDIM;
    float* gxr1 = (float*)(ring2 + (size_t)DRING * HDIM);
    float* gxr2 = gxr1 + (size_t)GXRING * FOURH;

    hipMemsetAsync(syncw, 0, SYNC_BYTES, stream);

    // gx0 = x @ W_ih0^T + b_ih0 + b_hh0
    {
        dim3 g(FOURH / 64, TSEQ / 64);
        gemm_bias_kernel<<<g, 256, 0, stream>>>(x, W_ih[0], b_ih[0], b_hh[0],
                                                gx, TSEQ, FOURH, HDIM);
    }

    // fused 3-layer pipelined scan + on-the-fly gx GEMMs: 256 blocks x 512 thr
    {
        const float* gx0_c = gx;
        float* h2 = A;
        void* args[] = {
            (void*)&gx0_c,
            (void*)&W_hh[0], (void*)&W_hh[1], (void*)&W_hh[2],
            (void*)&W_ih[1], (void*)&W_ih[2],
            (void*)&b_ih[1], (void*)&b_hh[1],
            (void*)&b_ih[2], (void*)&b_hh[2],
            (void*)&ring0, (void*)&ring1, (void*)&ring2,
            (void*)&gxr1, (void*)&gxr2,
            (void*)&h2, (void*)&syncw
        };
        hipLaunchCooperativeKernel((void*)fused_scan,
                                   dim3(3 * SCANB + 2 * GEMMB), dim3(512),
                                   args, 0, stream);
    }

    // out = h2 @ fc_w^T + fc_b
    {
        dim3 g(NCLS / 64, TSEQ / 64);
        gemm_bias_kernel<<<g, 256, 0, stream>>>(A, fc_w, fc_b, nullptr,
                                                out, TSEQ, NCLS, HDIM);
    }
}

// Round 10
// 7629.227 us; speedup vs baseline: 1.0128x; 1.0044x over previous
//
#include <hip/hip_runtime.h>

#define HDIM  1024
#define FOURH 4096
#define TSEQ  2048
#define NCLS  512

// ---- fused pipeline config: grid = 3*64 + 2*32 = 256 blocks x 512 thr ----
#define SCANB  64       // scan blocks per layer
#define GEMMB  32       // gemm blocks per group
#define U16    16       // hidden units per scan block
#define DRING  128      // h-ring depth (steps)
#define GXRING 128      // gx-ring depth (steps)
#define CHUNK  64       // gx chunk (steps)
#define NCHUNK 32       // 2048/64

// sync offsets (u32 units)
#define CNT0 0          // [32] chunk-arrive, gemm group 0
#define CNT1 64         // [32] chunk-arrive, gemm group 1
#define CD0  128        // chunks_done, group 0
#define CD1  192        // chunks_done, group 1
#define SP1  256        // scan progress, layer 1
#define SP2  320        // scan progress, layer 2
#define SP0  384        // scan progress, layer 0 (gemm A-gate)
#define SYNC_BYTES 2048
#define HDR_BYTES 32768

typedef float v2f __attribute__((ext_vector_type(2)));

// ---------------------------------------------------------------------------
union SharedU {
    struct { float h[HDIM]; float gate[4][U16]; } scan;      // ~4.4 KB
    struct { float As[16][72]; float Bs[16][132]; } gemm;    // ~12.8 KB
};

__device__ __forceinline__ unsigned long long ald(const unsigned long long* p) {
    return __hip_atomic_load(p, __ATOMIC_RELAXED, __HIP_MEMORY_SCOPE_AGENT);
}
__device__ __forceinline__ void ast(unsigned long long* p, unsigned long long v) {
    __hip_atomic_store(p, v, __ATOMIC_RELAXED, __HIP_MEMORY_SCOPE_AGENT);
}
__device__ __forceinline__ unsigned ald32(const unsigned* p) {
    return __hip_atomic_load(p, __ATOMIC_RELAXED, __HIP_MEMORY_SCOPE_AGENT);
}
__device__ __forceinline__ void ast32(unsigned* p, unsigned v) {
    __hip_atomic_store(p, v, __ATOMIC_RELAXED, __HIP_MEMORY_SCOPE_AGENT);
}

__device__ __forceinline__ float fsig(float x)  { return 1.f / (1.f + __expf(-x)); }
// fast tanh: saturates to +/-1 at exp saturation, err ~1e-6 (proven r1/r2)
__device__ __forceinline__ float ftanh(float x) { return 1.f - 2.f / (1.f + __expf(2.f * x)); }

// ---------------------------------------------------------------------------
// GEMM: C[M,N] = A[M,K] * B[N,K]^T + bias1[N] (+ bias2[N] if non-null)
// (gx0 pre-pass and final FC) — unchanged, proven.
// ---------------------------------------------------------------------------
__global__ __launch_bounds__(256) void gemm_bias_kernel(
    const float* __restrict__ A, const float* __restrict__ B,
    const float* __restrict__ bias1, const float* __restrict__ bias2,
    float* __restrict__ C, int M, int N, int K)
{
    __shared__ float As[16][68];
    __shared__ float Bs[16][68];

    const int tid = threadIdx.x;
    const int tx = tid & 15;
    const int ty = tid >> 4;
    const int n0 = blockIdx.x * 64;
    const int m0 = blockIdx.y * 64;
    const int r  = tid >> 2;
    const int kq = tid & 3;

    float acc[4][4];
#pragma unroll
    for (int i = 0; i < 4; ++i)
#pragma unroll
        for (int j = 0; j < 4; ++j) acc[i][j] = 0.f;

    for (int k0 = 0; k0 < K; k0 += 16) {
        float4 va = *(const float4*)&A[(size_t)(m0 + r) * K + k0 + 4 * kq];
        float4 vb = *(const float4*)&B[(size_t)(n0 + r) * K + k0 + 4 * kq];
        As[4 * kq + 0][r] = va.x; As[4 * kq + 1][r] = va.y;
        As[4 * kq + 2][r] = va.z; As[4 * kq + 3][r] = va.w;
        Bs[4 * kq + 0][r] = vb.x; Bs[4 * kq + 1][r] = vb.y;
        Bs[4 * kq + 2][r] = vb.z; Bs[4 * kq + 3][r] = vb.w;
        __syncthreads();
#pragma unroll
        for (int kk = 0; kk < 16; ++kk) {
            float4 a = *(const float4*)&As[kk][4 * ty];
            float4 b = *(const float4*)&Bs[kk][4 * tx];
            acc[0][0] = fmaf(a.x, b.x, acc[0][0]);
            acc[0][1] = fmaf(a.x, b.y, acc[0][1]);
            acc[0][2] = fmaf(a.x, b.z, acc[0][2]);
            acc[0][3] = fmaf(a.x, b.w, acc[0][3]);
            acc[1][0] = fmaf(a.y, b.x, acc[1][0]);
            acc[1][1] = fmaf(a.y, b.y, acc[1][1]);
            acc[1][2] = fmaf(a.y, b.z, acc[1][2]);
            acc[1][3] = fmaf(a.y, b.w, acc[1][3]);
            acc[2][0] = fmaf(a.z, b.x, acc[2][0]);
            acc[2][1] = fmaf(a.z, b.y, acc[2][1]);
            acc[2][2] = fmaf(a.z, b.z, acc[2][2]);
            acc[2][3] = fmaf(a.z, b.w, acc[2][3]);
            acc[3][0] = fmaf(a.w, b.x, acc[3][0]);
            acc[3][1] = fmaf(a.w, b.y, acc[3][1]);
            acc[3][2] = fmaf(a.w, b.z, acc[3][2]);
            acc[3][3] = fmaf(a.w, b.w, acc[3][3]);
        }
        __syncthreads();
    }

    float4 bv = *(const float4*)&bias1[n0 + 4 * tx];
    if (bias2) {
        float4 b2 = *(const float4*)&bias2[n0 + 4 * tx];
        bv.x += b2.x; bv.y += b2.y; bv.z += b2.z; bv.w += b2.w;
    }
#pragma unroll
    for (int i = 0; i < 4; ++i) {
        const int row = m0 + 4 * ty + i;
        float4 o;
        o.x = acc[i][0] + bv.x;
        o.y = acc[i][1] + bv.y;
        o.z = acc[i][2] + bv.z;
        o.w = acc[i][3] + bv.w;
        *(float4*)&C[(size_t)row * N + n0 + 4 * tx] = o;
    }
}

// ---------------------------------------------------------------------------
// PIPELINE scan role — r9 structure + depth-2 ping-pong restage poll:
// two 8B loads kept permanently in flight (one per ring entry), waits at
// vmcnt(1) so checks complete at ~RT/2 intervals. Always-reissue keeps the
// vmcnt bookkeeping static; s_sleep(1) per 2 checks = r0's polite rate
// (<=2 outstanding/thread, unchanged). sched_barrier(0) + "+v" ties fence
// compiler reordering around the counted waits (guide rule 18).
// ---------------------------------------------------------------------------
#define LOAD_GXS(T) do { if (lane < 8) {                                      \
    gxs = __uint_as_float(ald32((const unsigned*)gxb +                        \
        (size_t)((T) & gxmask) * FOURH + (size_t)(lane >> 1) * HDIM           \
        + u0 + 2 * w + (lane & 1))); }                                        \
    gxrow = __shfl(gxs, lane & 7, 64); } while (0)

__device__ void scan_role(int bi,
    const float* __restrict__ Whh,
    const unsigned long long* __restrict__ gxb, unsigned gxmask,
    unsigned long long* __restrict__ ring,
    const unsigned* cdSrc,    // gx availability (null for layer 0)
    const unsigned* cdBp,     // h-ring backpressure (null for layer 2)
    unsigned* sp,             // scan progress out (all layers)
    float* __restrict__ h2,   // layer-2 history out (else null)
    SharedU* sm, unsigned* hcnt)
{
    const int tid  = threadIdx.x;
    const int w    = tid >> 6;         // 0..7
    const int lane = tid & 63;
    const int uu   = lane & 1;
    const int u0   = bi * U16;

    // weights: 8 rows per wave = gates{0..3} x units{u0+2w, u0+2w+1}
    // row rg: gate = rg>>1, unit-parity = rg&1 (r4/r6-verified layout)
    v2f wv[8][8];
#pragma unroll
    for (int rg = 0; rg < 8; ++rg) {
        const float* Wr = Whh +
            (size_t)((rg >> 1) * HDIM + u0 + 2 * w + (rg & 1)) * HDIM;
#pragma unroll
        for (int j = 0; j < 4; ++j) {
            const float4 q = *(const float4*)(Wr + 256 * j + 4 * lane);
            v2f qa = {q.x, q.y}, qb = {q.z, q.w};
            wv[rg][2 * j]     = qa;
            wv[rg][2 * j + 1] = qb;
        }
    }
    { float2 z = {0.f, 0.f}; *(float2*)(sm->scan.h + 2 * tid) = z; }
    if (tid == 0) *hcnt = 0u;
    float cst = 0.f;                   // cell state (valid on lanes 0,1)
    float gxs = 0.f;                   // gx value (valid on lanes 0..7)
    float gxrow = 0.f;                 // gx of row (lane&7), pre-gathered
    unsigned cdc = 0u, bpc = 0u;       // cached progress counters
    __syncthreads();

    for (int t = 0; t < TSEQ; ++t) {
        // ring overwrite backpressure: wave7 lane0 only (publish gate)
        if (cdBp && t >= DRING && w == 7 && lane == 0) {
            const unsigned need = (unsigned)((t - DRING) >> 6) + 1u;
            while (bpc < need) {
                bpc = ald32(cdBp);
                if (bpc < need) __builtin_amdgcn_s_sleep(4);
            }
        }
        if ((t & (CHUNK - 1)) == 0) {
            if (cdSrc && lane == 0) {           // each wave's lane0, cached
                const unsigned need = (unsigned)(t >> 6) + 1u;
                while (cdc < need) {
                    cdc = ald32(cdSrc);
                    if (cdc < need) __builtin_amdgcn_s_sleep(4);
                }
            }
            LOAD_GXS(t);
        }

        // dots: 8 rows/wave, packed f32 pairs (h staged at barrier B of t-1)
        v2f acc2[8];
#pragma unroll
        for (int rg = 0; rg < 8; ++rg) { v2f z = {0.f, 0.f}; acc2[rg] = z; }
#pragma unroll
        for (int j = 0; j < 4; ++j) {
            const float4 hq = *(const float4*)(sm->scan.h + 256 * j + 4 * lane);
            const v2f hA = {hq.x, hq.y};
            const v2f hB = {hq.z, hq.w};
#pragma unroll
            for (int rg = 0; rg < 8; ++rg) {
                acc2[rg] = __builtin_elementwise_fma(wv[rg][2 * j],     hA, acc2[rg]);
                acc2[rg] = __builtin_elementwise_fma(wv[rg][2 * j + 1], hB, acc2[rg]);
            }
        }
        float a[8];
#pragma unroll
        for (int rg = 0; rg < 8; ++rg) a[rg] = acc2[rg].x + acc2[rg].y;

        // reduce (r4/r6-verified): 3-stage intra-8, select, 3-stage cross
#pragma unroll
        for (int off = 1; off <= 4; off <<= 1)
#pragma unroll
            for (int rg = 0; rg < 8; ++rg)
                a[rg] += __shfl_xor(a[rg], off, 64);
        const int l7 = lane & 7;
        const float s0 = (l7 & 1) ? a[1] : a[0];
        const float s1 = (l7 & 1) ? a[3] : a[2];
        const float s2 = (l7 & 1) ? a[5] : a[4];
        const float s3 = (l7 & 1) ? a[7] : a[6];
        const float t0 = (l7 & 2) ? s1 : s0;
        const float t1 = (l7 & 2) ? s3 : s2;
        float x = (l7 & 4) ? t1 : t0;       // lane L: partial of row (L&7)
        x += __shfl_xor(x, 8, 64);
        x += __shfl_xor(x, 16, 64);
        x += __shfl_xor(x, 32, 64);         // lane L: total of row (L&7)
        x += gxrow;                          // + gx (same assoc as r6)

        // gather 4 gates for this lane's unit; pointwise on lanes 0,1
        float gsum[4];
#pragma unroll
        for (int g = 0; g < 4; ++g)
            gsum[g] = __shfl(x, 2 * g + uu, 64);
        {
            const float si = fsig(gsum[0]), sf = fsig(gsum[1]);
            const float tg = ftanh(gsum[2]), so = fsig(gsum[3]);
            cst = sf * cst + si * tg;
            const float hval = so * ftanh(cst);
            if (lane < 2) {
                sm->scan.gate[0][2 * w + lane] = hval;   // hstage
                if (h2) h2[(size_t)t * HDIM + u0 + 2 * w + lane] = hval;
            }
        }
        asm volatile("s_waitcnt lgkmcnt(0)" ::: "memory");  // hstage visible
        if (lane == 0)
            __hip_atomic_fetch_add(hcnt, 1u, __ATOMIC_RELAXED,
                                   __HIP_MEMORY_SCOPE_WORKGROUP);

        const unsigned tag = (unsigned)(t + 1);
        if (w == 7) {
            // wait for all 8 waves' hstage, then publish ONE 128B line
            const unsigned needC = 8u * (unsigned)(t + 1);
            while (__hip_atomic_load(hcnt, __ATOMIC_RELAXED,
                                     __HIP_MEMORY_SCOPE_WORKGROUP) < needC) {}
            asm volatile("s_waitcnt lgkmcnt(0)" ::: "memory");
            __builtin_amdgcn_sched_barrier(0);
            if (lane < U16) {
                const float h = sm->scan.gate[0][lane];
                ast(ring + (size_t)(t & (DRING - 1)) * HDIM + u0 + lane,
                    ((unsigned long long)tag << 32) |
                    (unsigned long long)__float_as_uint(h));
            }
            if (sp && bi == 0 && lane == 0) ast32(sp, (unsigned)t);
        }
        if (((t + 1) & (CHUNK - 1)) != 0 && t + 1 < TSEQ) LOAD_GXS(t + 1);

        // restage h(t): depth-2 ping-pong tagged poll (2 in flight, waits at
        // vmcnt(1) -> checks at ~RT/2 intervals), then barriers + LDS stage.
        if (t + 1 < TSEQ) {
            const unsigned long long* hb = ring + (size_t)(t & (DRING - 1)) * HDIM;
            const unsigned long long* a0p = hb + 2 * tid;
            const unsigned long long* a1p = hb + 2 * tid + 1;
            unsigned long long y0, y1;
            unsigned h0 = 0, h1 = 0;
            bool got0 = false, got1 = false;
            asm volatile("global_load_dwordx2 %0, %1, off sc0 sc1"
                         : "=v"(y0) : "v"(a0p) : "memory");
            asm volatile("global_load_dwordx2 %0, %1, off sc0 sc1"
                         : "=v"(y1) : "v"(a1p) : "memory");
            __builtin_amdgcn_sched_barrier(0);
            for (;;) {
                asm volatile("s_waitcnt vmcnt(1)" : "+v"(y0) :: "memory");
                __builtin_amdgcn_sched_barrier(0);
                if (!got0 && (unsigned)(y0 >> 32) == tag) { h0 = (unsigned)y0; got0 = true; }
                if (got0 && got1) break;
                __builtin_amdgcn_sched_barrier(0);
                asm volatile("global_load_dwordx2 %0, %1, off sc0 sc1"
                             : "=v"(y0) : "v"(a0p) : "memory");
                asm volatile("s_waitcnt vmcnt(1)" : "+v"(y1) :: "memory");
                __builtin_amdgcn_sched_barrier(0);
                if (!got1 && (unsigned)(y1 >> 32) == tag) { h1 = (unsigned)y1; got1 = true; }
                if (got0 && got1) break;
                __builtin_amdgcn_sched_barrier(0);
                asm volatile("global_load_dwordx2 %0, %1, off sc0 sc1"
                             : "=v"(y1) : "v"(a1p) : "memory");
                __builtin_amdgcn_s_sleep(1);
            }
            asm volatile("s_waitcnt vmcnt(0)" ::: "memory");
            __builtin_amdgcn_sched_barrier(0);
            __syncthreads();   // barrier A: all waves past poll => dots done
            sm->scan.h[2 * tid]     = __uint_as_float(h0);
            sm->scan.h[2 * tid + 1] = __uint_as_float(h1);
            __syncthreads();   // barrier B: h(t) staged for all waves
        }
    }
}

// ---------------------------------------------------------------------------
// PIPELINE gemm role: 32 blocks x 512 thr per group; 128-col x 64-row chunks.
// A-staging gated on source-layer progress (r9); per-entry tag-poll retained
// for correctness (post-gate polls hit first try).
// ---------------------------------------------------------------------------
__device__ void gemm_role(int tix,
    const unsigned long long* __restrict__ ringS,
    const unsigned* __restrict__ spA,    // source-layer progress (A-gate)
    const float* __restrict__ Wih,
    const float* __restrict__ bih, const float* __restrict__ bhh,
    float* __restrict__ gxr,
    unsigned* cnt, unsigned* cd, const unsigned* spC,
    SharedU* sm)
{
    const int tid = threadIdx.x;
    const int tx = tid & 31, ty = tid >> 5;   // compute map: 128 cols, 64 rows
    const int n0 = tix * 128;
    const int tt = tid >> 3, ke = tid & 7;    // A staging: row tt, k-pair 2*ke
    const int cB = tid >> 2, kq = tid & 3;    // B staging: col cB, k-quad 4*kq

    float4 bv;
    {
        const float4 b1 = *(const float4*)(bih + n0 + 4 * tx);
        const float4 b2 = *(const float4*)(bhh + n0 + 4 * tx);
        bv.x = b1.x + b2.x; bv.y = b1.y + b2.y;
        bv.z = b1.z + b2.z; bv.w = b1.w + b2.w;
    }
    unsigned long long* gxr64 = (unsigned long long*)gxr;

    for (int q = 0; q < NCHUNK; ++q) {
        // gx-ring overwrite backpressure (victims = chunk q-2)
        if (q >= GXRING / CHUNK && tid == 0) {
            const unsigned need = (unsigned)((q - GXRING / CHUNK + 1) * CHUNK + 2);
            while (ald32(spC) < need) __builtin_amdgcn_s_sleep(8);
        }
        // A-gate: wait until the source layer has published this chunk's
        // last row (sp stores the just-completed step t; need t >= q*64+63).
        if (tid == 0) {
            const unsigned needA = (unsigned)(q * CHUNK + CHUNK - 1);
            while (ald32(spA) < needA) __builtin_amdgcn_s_sleep(16);
        }
        __syncthreads();

        float acc[4][4];
#pragma unroll
        for (int i = 0; i < 4; ++i)
#pragma unroll
            for (int j = 0; j < 4; ++j) acc[i][j] = 0.f;

        for (int k0 = 0; k0 < HDIM; k0 += 16) {
            {   // stage A (h chunk) with tag-poll: As[k][t]
                const int trow = q * CHUNK + tt;
                const unsigned expt = (unsigned)(trow + 1);
                const unsigned long long* srcp =
                    ringS + (size_t)(trow & (DRING - 1)) * HDIM + k0 + 2 * ke;
#pragma unroll
                for (int e = 0; e < 2; ++e) {
                    unsigned long long x;
                    while ((unsigned)((x = ald(srcp + e)) >> 32) != expt)
                        __builtin_amdgcn_s_sleep(1);
                    sm->gemm.As[2 * ke + e][tt] = __uint_as_float((unsigned)x);
                }
            }
            {   // stage B (W_ih tile)
                const float4 vb = *(const float4*)(Wih + (size_t)(n0 + cB) * HDIM + k0 + 4 * kq);
                sm->gemm.Bs[4 * kq + 0][cB] = vb.x;
                sm->gemm.Bs[4 * kq + 1][cB] = vb.y;
                sm->gemm.Bs[4 * kq + 2][cB] = vb.z;
                sm->gemm.Bs[4 * kq + 3][cB] = vb.w;
            }
            __syncthreads();
#pragma unroll
            for (int kk = 0; kk < 16; ++kk) {
                const float4 a = *(const float4*)&sm->gemm.As[kk][4 * ty];
                const float4 b = *(const float4*)&sm->gemm.Bs[kk][4 * tx];
                acc[0][0] = fmaf(a.x, b.x, acc[0][0]);
                acc[0][1] = fmaf(a.x, b.y, acc[0][1]);
                acc[0][2] = fmaf(a.x, b.z, acc[0][2]);
                acc[0][3] = fmaf(a.x, b.w, acc[0][3]);
                acc[1][0] = fmaf(a.y, b.x, acc[1][0]);
                acc[1][1] = fmaf(a.y, b.y, acc[1][1]);
                acc[1][2] = fmaf(a.y, b.z, acc[1][2]);
                acc[1][3] = fmaf(a.y, b.w, acc[1][3]);
                acc[2][0] = fmaf(a.z, b.x, acc[2][0]);
                acc[2][1] = fmaf(a.z, b.y, acc[2][1]);
                acc[2][2] = fmaf(a.z, b.z, acc[2][2]);
                acc[2][3] = fmaf(a.z, b.w, acc[2][3]);
                acc[3][0] = fmaf(a.w, b.x, acc[3][0]);
                acc[3][1] = fmaf(a.w, b.y, acc[3][1]);
                acc[3][2] = fmaf(a.w, b.z, acc[3][2]);
                acc[3][3] = fmaf(a.w, b.w, acc[3][3]);
            }
            __syncthreads();
        }

#pragma unroll
        for (int i = 0; i < 4; ++i) {
            const int trow = q * CHUNK + 4 * ty + i;
            const float o0 = acc[i][0] + bv.x;
            const float o1 = acc[i][1] + bv.y;
            const float o2 = acc[i][2] + bv.z;
            const float o3 = acc[i][3] + bv.w;
            const size_t base =
                ((size_t)(trow & (GXRING - 1)) * FOURH + n0 + 4 * tx) / 2;
            ast(gxr64 + base,
                ((unsigned long long)__float_as_uint(o1) << 32) | __float_as_uint(o0));
            ast(gxr64 + base + 1,
                ((unsigned long long)__float_as_uint(o3) << 32) | __float_as_uint(o2));
        }
        asm volatile("s_waitcnt vmcnt(0)" ::: "memory");
        __syncthreads();
        if (tid == 0) {
            const unsigned old = __hip_atomic_fetch_add(cnt + q, 1u,
                                     __ATOMIC_RELAXED, __HIP_MEMORY_SCOPE_AGENT);
            if (old + 1u == (unsigned)GEMMB) ast32(cd, (unsigned)(q + 1));
        }
    }
}

// ---------------------------------------------------------------------------
__global__ __launch_bounds__(512, 2) void fused_scan(
    const float* __restrict__ gx0,
    const float* __restrict__ Whh0, const float* __restrict__ Whh1,
    const float* __restrict__ Whh2,
    const float* __restrict__ Wih1, const float* __restrict__ Wih2,
    const float* __restrict__ bih1, const float* __restrict__ bhh1,
    const float* __restrict__ bih2, const float* __restrict__ bhh2,
    unsigned long long* ring0, unsigned long long* ring1, unsigned long long* ring2,
    float* gxr1, float* gxr2,
    float* h2out, unsigned* syncw)
{
    __shared__ SharedU sm;
    __shared__ unsigned hcnt;
    const int lb = blockIdx.x;
    if (lb < 3 * SCANB) {
        const int layer = lb >> 6;
        const int bi    = lb & 63;
        if (layer == 0)
            scan_role(bi, Whh0, (const unsigned long long*)gx0, 2047u, ring0,
                      nullptr, syncw + CD0, syncw + SP0, nullptr, &sm, &hcnt);
        else if (layer == 1)
            scan_role(bi, Whh1, (const unsigned long long*)gxr1, GXRING - 1u, ring1,
                      syncw + CD0, syncw + CD1, syncw + SP1, nullptr, &sm, &hcnt);
        else
            scan_role(bi, Whh2, (const unsigned long long*)gxr2, GXRING - 1u, ring2,
                      syncw + CD1, nullptr, syncw + SP2, h2out, &sm, &hcnt);
    } else {
        const int gb  = lb - 3 * SCANB;
        const int gl  = gb >> 5;
        const int tix = gb & 31;
        if (gl == 0)
            gemm_role(tix, ring0, syncw + SP0, Wih1, bih1, bhh1, gxr1,
                      syncw + CNT0, syncw + CD0, syncw + SP1, &sm);
        else
            gemm_role(tix, ring1, syncw + SP1, Wih2, bih2, bhh2, gxr2,
                      syncw + CNT1, syncw + CD1, syncw + SP2, &sm);
    }
}

// ---------------------------------------------------------------------------
extern "C" void kernel_launch(void* const* d_in, const int* in_sizes, int n_in,
                              void* d_out, int out_size, void* d_ws, size_t ws_size,
                              hipStream_t stream)
{
    (void)in_sizes; (void)n_in; (void)out_size; (void)ws_size;

    const float* x = (const float*)d_in[0];
    const float* W_ih[3] = {(const float*)d_in[1], (const float*)d_in[5], (const float*)d_in[9]};
    const float* W_hh[3] = {(const float*)d_in[2], (const float*)d_in[6], (const float*)d_in[10]};
    const float* b_ih[3] = {(const float*)d_in[3], (const float*)d_in[7], (const float*)d_in[11]};
    const float* b_hh[3] = {(const float*)d_in[4], (const float*)d_in[8], (const float*)d_in[12]};
    const float* fc_w = (const float*)d_in[13];
    const float* fc_b = (const float*)d_in[14];
    float* out = (float*)d_out;

    // ws: header 32KB | gx0 32MB | A 8MB (h2) | rings 3MB | gxr 4MB  (49.3MB)
    unsigned* syncw = (unsigned*)d_ws;
    float* gx = (float*)((char*)d_ws + HDR_BYTES);
    float* A  = gx + (size_t)TSEQ * FOURH;
    unsigned long long* ring0 = (unsigned long long*)(A + (size_t)TSEQ * HDIM);
    unsigned long long* ring1 = ring0 + (size_t)DRING * HDIM;
    unsigned long long* ring2 = ring1 + (size_t)DRING * HDIM;
    float* gxr1 = (float*)(ring2 + (size_t)DRING * HDIM);
    float* gxr2 = gxr1 + (size_t)GXRING * FOURH;

    hipMemsetAsync(syncw, 0, SYNC_BYTES, stream);

    // gx0 = x @ W_ih0^T + b_ih0 + b_hh0
    {
        dim3 g(FOURH / 64, TSEQ / 64);
        gemm_bias_kernel<<<g, 256, 0, stream>>>(x, W_ih[0], b_ih[0], b_hh[0],
                                                gx, TSEQ, FOURH, HDIM);
    }

    // fused 3-layer pipelined scan + on-the-fly gx GEMMs: 256 blocks x 512 thr
    {
        const float* gx0_c = gx;
        float* h2 = A;
        void* args[] = {
            (void*)&gx0_c,
            (void*)&W_hh[0], (void*)&W_hh[1], (void*)&W_hh[2],
            (void*)&W_ih[1], (void*)&W_ih[2],
            (void*)&b_ih[1], (void*)&b_hh[1],
            (void*)&b_ih[2], (void*)&b_hh[2],
            (void*)&ring0, (void*)&ring1, (void*)&ring2,
            (void*)&gxr1, (void*)&gxr2,
            (void*)&h2, (void*)&syncw
        };
        hipLaunchCooperativeKernel((void*)fused_scan,
                                   dim3(3 * SCANB + 2 * GEMMB), dim3(512),
                                   args, 0, stream);
    }

    // out = h2 @ fc_w^T + fc_b
    {
        dim3 g(NCLS / 64, TSEQ / 64);
        gemm_bias_kernel<<<g, 256, 0, stream>>>(A, fc_w, fc_b, nullptr,
                                                out, TSEQ, NCLS, HDIM);
    }
}